// Round 4
// baseline (243.680 us; speedup 1.0000x reference)
//
#include <hip/hip_runtime.h>
#include <hip/hip_bf16.h>

// ---------------------------------------------------------------------------
// 2-layer GCN on MI355X, round 4.
//   - CSR build: count atomic returns slot; scatter atomic-free (4 B payload)
//   - GEMM: fp32 VALU, full-K A tile staged once (aligned b128, conflict-free),
//     interleaved B column ownership (cols h*64+tx*4+j) -> all LDS b128 reads
//     hit uniform bank positions. dinv folded into epilogue, bf16 output.
//   - z1 stored bf16 (agg1 output = gemm2 input): saves ~25 MB traffic.
//   - agg: out_i = dinv_i * (g_i + sum g_src) + b ; pure adds, unroll 8.
// ---------------------------------------------------------------------------

__device__ __forceinline__ float bf_lo(unsigned u) { return __uint_as_float(u << 16); }
__device__ __forceinline__ float bf_hi(unsigned u) { return __uint_as_float(u & 0xffff0000u); }
__device__ __forceinline__ unsigned short f2bf(float f) {
    return (unsigned short)(__bfloat16_as_ushort(__float2bfloat16(f)));
}

__global__ __launch_bounds__(256) void zero_kernel(int* __restrict__ a, int n) {
    int i = blockIdx.x * 256 + threadIdx.x;
    if (i < n) a[i] = 0;
}

// count in-degree; atomic return value IS the CSR slot for this edge
__global__ __launch_bounds__(256) void count_kernel(const int* __restrict__ dst,
                                                    int* __restrict__ cnt,
                                                    int* __restrict__ eslot, int E) {
    int e = blockIdx.x * 256 + threadIdx.x;
    if (e < E) eslot[e] = atomicAdd(&cnt[dst[e]], 1);
}

// exclusive scan pass 1 + fused dinv = rsqrt(deg+1)
__global__ __launch_bounds__(256) void scan1_kernel(const int* __restrict__ cnt,
                                                    int* __restrict__ row_ptr,
                                                    int* __restrict__ blksum,
                                                    float* __restrict__ dinv, int N) {
    __shared__ int sm[256];
    int i = blockIdx.x * 256 + threadIdx.x;
    int v = (i < N) ? cnt[i] : 0;
    if (i < N) dinv[i] = rsqrtf((float)(v + 1));
    sm[threadIdx.x] = v;
    __syncthreads();
    for (int off = 1; off < 256; off <<= 1) {
        int t = (threadIdx.x >= off) ? sm[threadIdx.x - off] : 0;
        __syncthreads();
        sm[threadIdx.x] += t;
        __syncthreads();
    }
    if (i < N) row_ptr[i] = sm[threadIdx.x] - v;
    if (threadIdx.x == 255) blksum[blockIdx.x] = sm[255];
}

__global__ __launch_bounds__(256) void scan2_kernel(int* __restrict__ blksum, int nb) {
    __shared__ int sm[256];
    int i = threadIdx.x;
    int v = (i < nb) ? blksum[i] : 0;
    sm[i] = v;
    __syncthreads();
    for (int off = 1; off < 256; off <<= 1) {
        int t = (i >= off) ? sm[i - off] : 0;
        __syncthreads();
        sm[i] += t;
        __syncthreads();
    }
    if (i < nb) blksum[i] = sm[i] - v;
}

__global__ __launch_bounds__(256) void scan3_kernel(int* __restrict__ row_ptr,
                                                    const int* __restrict__ blksum,
                                                    int N, int E) {
    int i = blockIdx.x * 256 + threadIdx.x;
    if (i < N) row_ptr[i] += blksum[blockIdx.x];
    if (i == 0) row_ptr[N] = E;
}

// atomic-free scatter: slot precomputed by count_kernel
__global__ __launch_bounds__(256) void scatter_kernel(const int* __restrict__ src,
                                                      const int* __restrict__ dst,
                                                      const int* __restrict__ row_ptr,
                                                      const int* __restrict__ eslot,
                                                      int* __restrict__ ssrc, int E) {
    int e = blockIdx.x * 256 + threadIdx.x;
    if (e < E) {
        int p = row_ptr[dst[e]] + eslot[e];
        ssrc[p] = src[e];
    }
}

// --- GEMM: C[N,M](bf16) = dinv[row] * (A[N,128] @ W[128,M]) ----------------
// A fp32 (ABF16=false) or bf16 (ABF16=true). 64-row tile, 256 thr:
// tx=tid&15 owns cols {h*64 + tx*4 + j : h<M/64, j<4}, ty=tid>>4 owns 4 rows.
// Full A tile (64x128) staged once; B staged in 32-k chunks.
template <int M, bool ABF16>
__global__ __launch_bounds__(256) void gemm_kernel(const void* __restrict__ Araw,
                                                   const float* __restrict__ W,
                                                   const float* __restrict__ dinv,
                                                   unsigned short* __restrict__ C,
                                                   int N) {
    constexpr int K = 128, KC = 32, TN = M / 16, NH = M / 64;  // NH col-groups of 4
    __shared__ float Bs[KC][M];
    __shared__ float AsF[ABF16 ? 1 : 64 * K];
    __shared__ unsigned short AsH[ABF16 ? 64 * K : 1];

    const int tid = threadIdx.x;
    const int tx = tid & 15;
    const int ty = tid >> 4;
    const int row0 = blockIdx.x * 64;

    // ---- stage full A tile ----
    if constexpr (!ABF16) {
        const float* A = (const float*)Araw;
#pragma unroll
        for (int f = 0; f < 8; ++f) {  // 2048 float4
            int q = tid + 256 * f;
            int r = q >> 5;
            int c4 = (q & 31) << 2;
            int grow = row0 + r;
            float4 v = make_float4(0.f, 0.f, 0.f, 0.f);
            if (grow < N) v = *(const float4*)(A + (size_t)grow * K + c4);
            *(float4*)&AsF[r * K + c4] = v;  // aligned b128, conflict-free
        }
    } else {
        const unsigned short* A = (const unsigned short*)Araw;
#pragma unroll
        for (int f = 0; f < 4; ++f) {  // 1024 x 16B chunks
            int q = tid + 256 * f;
            int r = q >> 4;
            int ch = q & 15;  // 8 ushorts per chunk
            int grow = row0 + r;
            uint4 v = {0u, 0u, 0u, 0u};
            if (grow < N) v = *(const uint4*)(A + (size_t)grow * K + ch * 8);
            *(uint4*)&AsH[r * K + ch * 8] = v;
        }
    }

    float acc[4][TN];
#pragma unroll
    for (int i = 0; i < 4; ++i)
#pragma unroll
        for (int j = 0; j < TN; ++j) acc[i][j] = 0.f;

    for (int kc = 0; kc < K; kc += KC) {
        // stage B chunk (32 x M), straight float4 copy
        constexpr int BQ = KC * M / 4;
#pragma unroll
        for (int f = 0; f < BQ / 256; ++f) {
            int q = tid + 256 * f;
            int r = q / (M / 4);
            int c4 = (q % (M / 4)) << 2;
            *(float4*)(&Bs[r][c4]) = *(const float4*)(W + (size_t)(kc + r) * M + c4);
        }
        __syncthreads();

        if constexpr (!ABF16) {
#pragma unroll
            for (int k4 = 0; k4 < KC / 4; ++k4) {
                int kk = kc + k4 * 4;
                float4 a4[4];
#pragma unroll
                for (int i = 0; i < 4; ++i)
                    a4[i] = *(const float4*)&AsF[(ty * 4 + i) * K + kk];  // broadcast
#pragma unroll
                for (int k2 = 0; k2 < 4; ++k2) {
                    int kl = k4 * 4 + k2;
                    float4 b[NH];
#pragma unroll
                    for (int h = 0; h < NH; ++h)
                        b[h] = *(const float4*)&Bs[kl][h * 64 + tx * 4];
#pragma unroll
                    for (int i = 0; i < 4; ++i) {
                        float a = ((const float*)&a4[i])[k2];
#pragma unroll
                        for (int h = 0; h < NH; ++h) {
                            acc[i][h * 4 + 0] += a * b[h].x;
                            acc[i][h * 4 + 1] += a * b[h].y;
                            acc[i][h * 4 + 2] += a * b[h].z;
                            acc[i][h * 4 + 3] += a * b[h].w;
                        }
                    }
                }
            }
        } else {
#pragma unroll
            for (int k8 = 0; k8 < KC / 8; ++k8) {
                int kk = kc + k8 * 8;
                float a[4][8];
#pragma unroll
                for (int i = 0; i < 4; ++i) {
                    uint4 u = *(const uint4*)&AsH[(ty * 4 + i) * K + kk];
                    a[i][0] = bf_lo(u.x); a[i][1] = bf_hi(u.x);
                    a[i][2] = bf_lo(u.y); a[i][3] = bf_hi(u.y);
                    a[i][4] = bf_lo(u.z); a[i][5] = bf_hi(u.z);
                    a[i][6] = bf_lo(u.w); a[i][7] = bf_hi(u.w);
                }
#pragma unroll
                for (int k2 = 0; k2 < 8; ++k2) {
                    int kl = k8 * 8 + k2;
                    float4 b[NH];
#pragma unroll
                    for (int h = 0; h < NH; ++h)
                        b[h] = *(const float4*)&Bs[kl][h * 64 + tx * 4];
#pragma unroll
                    for (int i = 0; i < 4; ++i) {
                        float av = a[i][k2];
#pragma unroll
                        for (int h = 0; h < NH; ++h) {
                            acc[i][h * 4 + 0] += av * b[h].x;
                            acc[i][h * 4 + 1] += av * b[h].y;
                            acc[i][h * 4 + 2] += av * b[h].z;
                            acc[i][h * 4 + 3] += av * b[h].w;
                        }
                    }
                }
            }
        }
        __syncthreads();
    }

    // epilogue: scale by dinv[row], pack bf16, 8 B stores per col-group
#pragma unroll
    for (int i = 0; i < 4; ++i) {
        int grow = row0 + ty * 4 + i;
        if (grow < N) {
            float dv = dinv[grow];
#pragma unroll
            for (int h = 0; h < NH; ++h) {
                unsigned short u0 = f2bf(acc[i][h * 4 + 0] * dv);
                unsigned short u1 = f2bf(acc[i][h * 4 + 1] * dv);
                unsigned short u2 = f2bf(acc[i][h * 4 + 2] * dv);
                unsigned short u3 = f2bf(acc[i][h * 4 + 3] * dv);
                uint2 pk;
                pk.x = (unsigned)u0 | ((unsigned)u1 << 16);
                pk.y = (unsigned)u2 | ((unsigned)u3 << 16);
                *(uint2*)(C + (size_t)grow * M + h * 64 + tx * 4) = pk;
            }
        }
    }
}

// --- CSR aggregation (pre-scaled g): one wave per node ---------------------
// out[i] = dinv_i * ( g_i + sum_{e: dst=i} g_src ) + b   [+relu]
// OUTBF16: write bf16 (feeds next GEMM); else fp32.
template <int M, bool RELU, bool OUTBF16>
__global__ __launch_bounds__(256) void agg_kernel(const unsigned short* __restrict__ g,
                                                  const int* __restrict__ row_ptr,
                                                  const int* __restrict__ ssrc,
                                                  const float* __restrict__ dinv,
                                                  const float* __restrict__ bias,
                                                  void* __restrict__ outraw, int N) {
    int node = __builtin_amdgcn_readfirstlane((int)(blockIdx.x * 4 + (threadIdx.x >> 6)));
    if (node >= N) return;
    int lane = threadIdx.x & 63;
    float di = dinv[node];
    int beg = row_ptr[node];
    int end = row_ptr[node + 1];

    if constexpr (M == 128) {
        const unsigned* hp = (const unsigned*)g;  // 2 bf16 per uint
        unsigned hv = hp[node * 64 + lane];
        float ax0 = bf_lo(hv), ay0 = bf_hi(hv);
        float ax1 = 0.f, ay1 = 0.f;
        int j = beg;
        for (; j + 7 < end; j += 8) {
            int s0 = ssrc[j + 0], s1 = ssrc[j + 1], s2 = ssrc[j + 2], s3 = ssrc[j + 3];
            int s4 = ssrc[j + 4], s5 = ssrc[j + 5], s6 = ssrc[j + 6], s7 = ssrc[j + 7];
            unsigned v0 = hp[s0 * 64 + lane], v1 = hp[s1 * 64 + lane];
            unsigned v2 = hp[s2 * 64 + lane], v3 = hp[s3 * 64 + lane];
            unsigned v4 = hp[s4 * 64 + lane], v5 = hp[s5 * 64 + lane];
            unsigned v6 = hp[s6 * 64 + lane], v7 = hp[s7 * 64 + lane];
            ax0 += bf_lo(v0) + bf_lo(v1) + bf_lo(v2) + bf_lo(v3);
            ax1 += bf_lo(v4) + bf_lo(v5) + bf_lo(v6) + bf_lo(v7);
            ay0 += bf_hi(v0) + bf_hi(v1) + bf_hi(v2) + bf_hi(v3);
            ay1 += bf_hi(v4) + bf_hi(v5) + bf_hi(v6) + bf_hi(v7);
        }
        for (; j + 3 < end; j += 4) {
            int s0 = ssrc[j + 0], s1 = ssrc[j + 1], s2 = ssrc[j + 2], s3 = ssrc[j + 3];
            unsigned v0 = hp[s0 * 64 + lane], v1 = hp[s1 * 64 + lane];
            unsigned v2 = hp[s2 * 64 + lane], v3 = hp[s3 * 64 + lane];
            ax0 += bf_lo(v0) + bf_lo(v1);
            ax1 += bf_lo(v2) + bf_lo(v3);
            ay0 += bf_hi(v0) + bf_hi(v1);
            ay1 += bf_hi(v2) + bf_hi(v3);
        }
        for (; j < end; ++j) {
            unsigned v = hp[ssrc[j] * 64 + lane];
            ax0 += bf_lo(v);
            ay0 += bf_hi(v);
        }
        float ax = (ax0 + ax1) * di + bias[2 * lane];
        float ay = (ay0 + ay1) * di + bias[2 * lane + 1];
        if (RELU) { ax = fmaxf(ax, 0.f); ay = fmaxf(ay, 0.f); }
        if constexpr (OUTBF16) {
            unsigned pk = (unsigned)f2bf(ax) | ((unsigned)f2bf(ay) << 16);
            ((unsigned*)outraw)[node * 64 + lane] = pk;
        } else {
            ((float2*)outraw)[node * 64 + lane] = make_float2(ax, ay);
        }
    } else {  // M == 64: one bf16 per lane
        float a0 = __uint_as_float((unsigned)g[node * 64 + lane] << 16);
        float a1 = 0.f;
        int j = beg;
        for (; j + 7 < end; j += 8) {
            int s0 = ssrc[j + 0], s1 = ssrc[j + 1], s2 = ssrc[j + 2], s3 = ssrc[j + 3];
            int s4 = ssrc[j + 4], s5 = ssrc[j + 5], s6 = ssrc[j + 6], s7 = ssrc[j + 7];
            float v0 = __uint_as_float((unsigned)g[s0 * 64 + lane] << 16);
            float v1 = __uint_as_float((unsigned)g[s1 * 64 + lane] << 16);
            float v2 = __uint_as_float((unsigned)g[s2 * 64 + lane] << 16);
            float v3 = __uint_as_float((unsigned)g[s3 * 64 + lane] << 16);
            float v4 = __uint_as_float((unsigned)g[s4 * 64 + lane] << 16);
            float v5 = __uint_as_float((unsigned)g[s5 * 64 + lane] << 16);
            float v6 = __uint_as_float((unsigned)g[s6 * 64 + lane] << 16);
            float v7 = __uint_as_float((unsigned)g[s7 * 64 + lane] << 16);
            a0 += v0 + v1 + v2 + v3;
            a1 += v4 + v5 + v6 + v7;
        }
        for (; j + 3 < end; j += 4) {
            int s0 = ssrc[j + 0], s1 = ssrc[j + 1], s2 = ssrc[j + 2], s3 = ssrc[j + 3];
            float v0 = __uint_as_float((unsigned)g[s0 * 64 + lane] << 16);
            float v1 = __uint_as_float((unsigned)g[s1 * 64 + lane] << 16);
            float v2 = __uint_as_float((unsigned)g[s2 * 64 + lane] << 16);
            float v3 = __uint_as_float((unsigned)g[s3 * 64 + lane] << 16);
            a0 += v0 + v1;
            a1 += v2 + v3;
        }
        for (; j < end; ++j)
            a0 += __uint_as_float((unsigned)g[ssrc[j] * 64 + lane] << 16);
        float acc = (a0 + a1) * di + bias[lane];
        if (RELU) acc = fmaxf(acc, 0.f);
        if constexpr (OUTBF16) {
            ((unsigned short*)outraw)[node * 64 + lane] = f2bf(acc);
        } else {
            ((float*)outraw)[node * 64 + lane] = acc;
        }
    }
}

extern "C" void kernel_launch(void* const* d_in, const int* in_sizes, int n_in,
                              void* d_out, int out_size, void* d_ws, size_t ws_size,
                              hipStream_t stream) {
    const float* x = (const float*)d_in[0];
    const int* eidx = (const int*)d_in[1];
    const float* W1 = (const float*)d_in[2];
    const float* b1 = (const float*)d_in[3];
    const float* W2 = (const float*)d_in[4];
    const float* b2 = (const float*)d_in[5];
    float* out = (float*)d_out;

    const int N = in_sizes[0] / 128;
    const int E = in_sizes[1] / 2;
    const int* src = eidx;
    const int* dst = eidx + E;

    char* ws = (char*)d_ws;
    size_t off = 0;
    auto alloc = [&](size_t bytes) -> char* {
        char* p = ws + off;
        off = (off + bytes + 255) & ~(size_t)255;
        return p;
    };
    int* cnt = (int*)alloc((size_t)N * 4);
    int* row_ptr = (int*)alloc((size_t)(N + 1) * 4);
    int* blksum = (int*)alloc(256 * 4);
    int* eslot = (int*)alloc((size_t)E * 4);
    int* ssrc = (int*)alloc((size_t)E * 4);
    float* dinv = (float*)alloc((size_t)N * 4);
    unsigned short* g1 = (unsigned short*)alloc((size_t)N * 128 * 2);  // bf16
    unsigned short* z1 = (unsigned short*)alloc((size_t)N * 128 * 2);  // bf16
    unsigned short* g2 = (unsigned short*)alloc((size_t)N * 64 * 2);   // bf16

    const int nbN = (N + 255) / 256;
    const int nbE = (E + 255) / 256;

    zero_kernel<<<nbN, 256, 0, stream>>>(cnt, N);
    count_kernel<<<nbE, 256, 0, stream>>>(dst, cnt, eslot, E);
    scan1_kernel<<<nbN, 256, 0, stream>>>(cnt, row_ptr, blksum, dinv, N);
    scan2_kernel<<<1, 256, 0, stream>>>(blksum, nbN);
    scan3_kernel<<<nbN, 256, 0, stream>>>(row_ptr, blksum, N, E);
    scatter_kernel<<<nbE, 256, 0, stream>>>(src, dst, row_ptr, eslot, ssrc, E);

    const int gb = (N + 63) / 64;
    gemm_kernel<128, false><<<gb, 256, 0, stream>>>(x, W1, dinv, g1, N);
    agg_kernel<128, true, true><<<(N + 3) / 4, 256, 0, stream>>>(g1, row_ptr, ssrc, dinv, b1, z1, N);
    gemm_kernel<64, true><<<gb, 256, 0, stream>>>(z1, W2, dinv, g2, N);
    agg_kernel<64, false, false><<<(N + 3) / 4, 256, 0, stream>>>(g2, row_ptr, ssrc, dinv, b2, out, N);
}

// Round 5
// 210.480 us; speedup vs baseline: 1.1577x; 1.1577x over previous
//
#include <hip/hip_runtime.h>
#include <hip/hip_bf16.h>

// ---------------------------------------------------------------------------
// 2-layer GCN on MI355X, round 5.
//   - CSR build: count atomic returns slot; scatter atomic-free (4 B payload)
//   - GEMMs now bf16 MFMA (16x16x32), NO LDS: A-frags gathered from global
//     (fp32 converted in-register for layer 1), W pre-packed into fragment
//     order by a tiny kernel. dinv folded into epilogue, bf16 output.
//   - agg: out_i = dinv_i * (g_i + sum g_src) + b ; pure adds, unroll 8.
// ---------------------------------------------------------------------------

typedef __attribute__((ext_vector_type(8))) short short8;
typedef __attribute__((ext_vector_type(4))) float f32x4;

__device__ __forceinline__ float bf_lo(unsigned u) { return __uint_as_float(u << 16); }
__device__ __forceinline__ float bf_hi(unsigned u) { return __uint_as_float(u & 0xffff0000u); }
__device__ __forceinline__ unsigned short f2bf(float f) {
    return (unsigned short)(__bfloat16_as_ushort(__float2bfloat16(f)));
}

__global__ __launch_bounds__(256) void zero_kernel(int* __restrict__ a, int n) {
    int i = blockIdx.x * 256 + threadIdx.x;
    if (i < n) a[i] = 0;
}

// count in-degree; atomic return value IS the CSR slot for this edge
__global__ __launch_bounds__(256) void count_kernel(const int* __restrict__ dst,
                                                    int* __restrict__ cnt,
                                                    int* __restrict__ eslot, int E) {
    int e = blockIdx.x * 256 + threadIdx.x;
    if (e < E) eslot[e] = atomicAdd(&cnt[dst[e]], 1);
}

// exclusive scan pass 1 + fused dinv = rsqrt(deg+1)
__global__ __launch_bounds__(256) void scan1_kernel(const int* __restrict__ cnt,
                                                    int* __restrict__ row_ptr,
                                                    int* __restrict__ blksum,
                                                    float* __restrict__ dinv, int N) {
    __shared__ int sm[256];
    int i = blockIdx.x * 256 + threadIdx.x;
    int v = (i < N) ? cnt[i] : 0;
    if (i < N) dinv[i] = rsqrtf((float)(v + 1));
    sm[threadIdx.x] = v;
    __syncthreads();
    for (int off = 1; off < 256; off <<= 1) {
        int t = (threadIdx.x >= off) ? sm[threadIdx.x - off] : 0;
        __syncthreads();
        sm[threadIdx.x] += t;
        __syncthreads();
    }
    if (i < N) row_ptr[i] = sm[threadIdx.x] - v;
    if (threadIdx.x == 255) blksum[blockIdx.x] = sm[255];
}

__global__ __launch_bounds__(256) void scan2_kernel(int* __restrict__ blksum, int nb) {
    __shared__ int sm[256];
    int i = threadIdx.x;
    int v = (i < nb) ? blksum[i] : 0;
    sm[i] = v;
    __syncthreads();
    for (int off = 1; off < 256; off <<= 1) {
        int t = (i >= off) ? sm[i - off] : 0;
        __syncthreads();
        sm[i] += t;
        __syncthreads();
    }
    if (i < nb) blksum[i] = sm[i] - v;
}

__global__ __launch_bounds__(256) void scan3_kernel(int* __restrict__ row_ptr,
                                                    const int* __restrict__ blksum,
                                                    int N, int E) {
    int i = blockIdx.x * 256 + threadIdx.x;
    if (i < N) row_ptr[i] += blksum[blockIdx.x];
    if (i == 0) row_ptr[N] = E;
}

// atomic-free scatter: slot precomputed by count_kernel
__global__ __launch_bounds__(256) void scatter_kernel(const int* __restrict__ src,
                                                      const int* __restrict__ dst,
                                                      const int* __restrict__ row_ptr,
                                                      const int* __restrict__ eslot,
                                                      int* __restrict__ ssrc, int E) {
    int e = blockIdx.x * 256 + threadIdx.x;
    if (e < E) {
        int p = row_ptr[dst[e]] + eslot[e];
        ssrc[p] = src[e];
    }
}

// pack W[128][ncol] fp32 -> Wp bf16 fragment order: Wp[(kb*ncol + n)*8 + j] =
// bf16(W[(kb*8+j)*ncol + n]), kb<16. A B-frag (k-chunk c, quad q, col n) is then
// the 16 B chunk at index (c*4+q)*ncol + n.
__global__ __launch_bounds__(256) void packw_kernel(const float* __restrict__ W,
                                                    unsigned short* __restrict__ Wp,
                                                    int ncol) {
    int i = blockIdx.x * 256 + threadIdx.x;
    if (i < 128 * ncol) {
        int j = i & 7;
        int n = (i >> 3) % ncol;
        int kb = i / (8 * ncol);
        Wp[i] = f2bf(W[(kb * 8 + j) * ncol + n]);
    }
}

// --- MFMA GEMM: C[N,M](bf16) = dinv[row] * (A[N,128] @ W[128,M]) -----------
// 16x16x32 bf16 MFMA, no LDS. Wave computes 16 rows x M cols (M/16 col tiles).
// Block = 4 waves = 64 rows. A fp32 (ABF16=false, converted in-reg) or bf16.
template <int M, bool ABF16>
__global__ __launch_bounds__(256) void mfma_gemm_kernel(const void* __restrict__ Araw,
                                                        const unsigned short* __restrict__ Wp,
                                                        const float* __restrict__ dinv,
                                                        unsigned short* __restrict__ C,
                                                        int N) {
    constexpr int NT = M / 16;  // col tiles
    const int lane = threadIdx.x & 63;
    const int wave = threadIdx.x >> 6;
    const int col = lane & 15;
    const int quad = lane >> 4;
    const int row0w = (blockIdx.x * 4 + wave) * 16;

    int arow = row0w + col;
    if (arow >= N) arow = N - 1;  // clamp (dup rows discarded at store)

    // ---- A fragments: afr[c] covers k = c*32 + quad*8 .. +7 ----
    short8 afr[4];
    if constexpr (!ABF16) {
        const float* Xr = (const float*)Araw + (size_t)arow * 128;
#pragma unroll
        for (int c = 0; c < 4; ++c) {
            float4 f0 = *(const float4*)(Xr + c * 32 + quad * 8);
            float4 f1 = *(const float4*)(Xr + c * 32 + quad * 8 + 4);
            short8 a;
            a[0] = (short)f2bf(f0.x); a[1] = (short)f2bf(f0.y);
            a[2] = (short)f2bf(f0.z); a[3] = (short)f2bf(f0.w);
            a[4] = (short)f2bf(f1.x); a[5] = (short)f2bf(f1.y);
            a[6] = (short)f2bf(f1.z); a[7] = (short)f2bf(f1.w);
            afr[c] = a;
        }
    } else {
        const uint4* Z = (const uint4*)Araw;  // 8 bf16 per uint4, row = 16 chunks
#pragma unroll
        for (int c = 0; c < 4; ++c) {
            union { uint4 u; short8 s; } cv;
            cv.u = Z[(size_t)arow * 16 + c * 4 + quad];
            afr[c] = cv.s;
        }
    }

    f32x4 acc[NT];
#pragma unroll
    for (int t = 0; t < NT; ++t) acc[t] = (f32x4){0.f, 0.f, 0.f, 0.f};

    const uint4* Wq = (const uint4*)Wp;
#pragma unroll
    for (int c = 0; c < 4; ++c) {
        short8 bfr[NT];
#pragma unroll
        for (int t = 0; t < NT; ++t) {
            union { uint4 u; short8 s; } cv;
            cv.u = Wq[(size_t)(c * 4 + quad) * M + t * 16 + col];
            bfr[t] = cv.s;
        }
#pragma unroll
        for (int t = 0; t < NT; ++t)
            acc[t] = __builtin_amdgcn_mfma_f32_16x16x32_bf16(afr[c], bfr[t], acc[t], 0, 0, 0);
    }

    // ---- epilogue: C row = row0w + quad*4 + r, col = t*16 + col ----
#pragma unroll
    for (int r = 0; r < 4; ++r) {
        int row = row0w + quad * 4 + r;
        if (row < N) {
            float dv = dinv[row];
#pragma unroll
            for (int t = 0; t < NT; ++t)
                C[(size_t)row * M + t * 16 + col] = f2bf(acc[t][r] * dv);
        }
    }
}

// --- CSR aggregation (pre-scaled g): one wave per node ---------------------
// out[i] = dinv_i * ( g_i + sum_{e: dst=i} g_src ) + b   [+relu]
template <int M, bool RELU, bool OUTBF16>
__global__ __launch_bounds__(256) void agg_kernel(const unsigned short* __restrict__ g,
                                                  const int* __restrict__ row_ptr,
                                                  const int* __restrict__ ssrc,
                                                  const float* __restrict__ dinv,
                                                  const float* __restrict__ bias,
                                                  void* __restrict__ outraw, int N) {
    int node = __builtin_amdgcn_readfirstlane((int)(blockIdx.x * 4 + (threadIdx.x >> 6)));
    if (node >= N) return;
    int lane = threadIdx.x & 63;
    float di = dinv[node];
    int beg = row_ptr[node];
    int end = row_ptr[node + 1];

    if constexpr (M == 128) {
        const unsigned* hp = (const unsigned*)g;  // 2 bf16 per uint
        unsigned hv = hp[node * 64 + lane];
        float ax0 = bf_lo(hv), ay0 = bf_hi(hv);
        float ax1 = 0.f, ay1 = 0.f;
        int j = beg;
        for (; j + 7 < end; j += 8) {
            int s0 = ssrc[j + 0], s1 = ssrc[j + 1], s2 = ssrc[j + 2], s3 = ssrc[j + 3];
            int s4 = ssrc[j + 4], s5 = ssrc[j + 5], s6 = ssrc[j + 6], s7 = ssrc[j + 7];
            unsigned v0 = hp[s0 * 64 + lane], v1 = hp[s1 * 64 + lane];
            unsigned v2 = hp[s2 * 64 + lane], v3 = hp[s3 * 64 + lane];
            unsigned v4 = hp[s4 * 64 + lane], v5 = hp[s5 * 64 + lane];
            unsigned v6 = hp[s6 * 64 + lane], v7 = hp[s7 * 64 + lane];
            ax0 += bf_lo(v0) + bf_lo(v1) + bf_lo(v2) + bf_lo(v3);
            ax1 += bf_lo(v4) + bf_lo(v5) + bf_lo(v6) + bf_lo(v7);
            ay0 += bf_hi(v0) + bf_hi(v1) + bf_hi(v2) + bf_hi(v3);
            ay1 += bf_hi(v4) + bf_hi(v5) + bf_hi(v6) + bf_hi(v7);
        }
        for (; j + 3 < end; j += 4) {
            int s0 = ssrc[j + 0], s1 = ssrc[j + 1], s2 = ssrc[j + 2], s3 = ssrc[j + 3];
            unsigned v0 = hp[s0 * 64 + lane], v1 = hp[s1 * 64 + lane];
            unsigned v2 = hp[s2 * 64 + lane], v3 = hp[s3 * 64 + lane];
            ax0 += bf_lo(v0) + bf_lo(v1);
            ax1 += bf_lo(v2) + bf_lo(v3);
            ay0 += bf_hi(v0) + bf_hi(v1);
            ay1 += bf_hi(v2) + bf_hi(v3);
        }
        for (; j < end; ++j) {
            unsigned v = hp[ssrc[j] * 64 + lane];
            ax0 += bf_lo(v);
            ay0 += bf_hi(v);
        }
        float ax = (ax0 + ax1) * di + bias[2 * lane];
        float ay = (ay0 + ay1) * di + bias[2 * lane + 1];
        if (RELU) { ax = fmaxf(ax, 0.f); ay = fmaxf(ay, 0.f); }
        if constexpr (OUTBF16) {
            unsigned pk = (unsigned)f2bf(ax) | ((unsigned)f2bf(ay) << 16);
            ((unsigned*)outraw)[node * 64 + lane] = pk;
        } else {
            ((float2*)outraw)[node * 64 + lane] = make_float2(ax, ay);
        }
    } else {  // M == 64: one bf16 per lane
        float a0 = __uint_as_float((unsigned)g[node * 64 + lane] << 16);
        float a1 = 0.f;
        int j = beg;
        for (; j + 7 < end; j += 8) {
            int s0 = ssrc[j + 0], s1 = ssrc[j + 1], s2 = ssrc[j + 2], s3 = ssrc[j + 3];
            int s4 = ssrc[j + 4], s5 = ssrc[j + 5], s6 = ssrc[j + 6], s7 = ssrc[j + 7];
            float v0 = __uint_as_float((unsigned)g[s0 * 64 + lane] << 16);
            float v1 = __uint_as_float((unsigned)g[s1 * 64 + lane] << 16);
            float v2 = __uint_as_float((unsigned)g[s2 * 64 + lane] << 16);
            float v3 = __uint_as_float((unsigned)g[s3 * 64 + lane] << 16);
            float v4 = __uint_as_float((unsigned)g[s4 * 64 + lane] << 16);
            float v5 = __uint_as_float((unsigned)g[s5 * 64 + lane] << 16);
            float v6 = __uint_as_float((unsigned)g[s6 * 64 + lane] << 16);
            float v7 = __uint_as_float((unsigned)g[s7 * 64 + lane] << 16);
            a0 += v0 + v1 + v2 + v3;
            a1 += v4 + v5 + v6 + v7;
        }
        for (; j + 3 < end; j += 4) {
            int s0 = ssrc[j + 0], s1 = ssrc[j + 1], s2 = ssrc[j + 2], s3 = ssrc[j + 3];
            float v0 = __uint_as_float((unsigned)g[s0 * 64 + lane] << 16);
            float v1 = __uint_as_float((unsigned)g[s1 * 64 + lane] << 16);
            float v2 = __uint_as_float((unsigned)g[s2 * 64 + lane] << 16);
            float v3 = __uint_as_float((unsigned)g[s3 * 64 + lane] << 16);
            a0 += v0 + v1;
            a1 += v2 + v3;
        }
        for (; j < end; ++j)
            a0 += __uint_as_float((unsigned)g[ssrc[j] * 64 + lane] << 16);
        float acc = (a0 + a1) * di + bias[lane];
        if (RELU) acc = fmaxf(acc, 0.f);
        if constexpr (OUTBF16) {
            ((unsigned short*)outraw)[node * 64 + lane] = f2bf(acc);
        } else {
            ((float*)outraw)[node * 64 + lane] = acc;
        }
    }
}

extern "C" void kernel_launch(void* const* d_in, const int* in_sizes, int n_in,
                              void* d_out, int out_size, void* d_ws, size_t ws_size,
                              hipStream_t stream) {
    const float* x = (const float*)d_in[0];
    const int* eidx = (const int*)d_in[1];
    const float* W1 = (const float*)d_in[2];
    const float* b1 = (const float*)d_in[3];
    const float* W2 = (const float*)d_in[4];
    const float* b2 = (const float*)d_in[5];
    float* out = (float*)d_out;

    const int N = in_sizes[0] / 128;
    const int E = in_sizes[1] / 2;
    const int* src = eidx;
    const int* dst = eidx + E;

    char* ws = (char*)d_ws;
    size_t off = 0;
    auto alloc = [&](size_t bytes) -> char* {
        char* p = ws + off;
        off = (off + bytes + 255) & ~(size_t)255;
        return p;
    };
    int* cnt = (int*)alloc((size_t)N * 4);
    int* row_ptr = (int*)alloc((size_t)(N + 1) * 4);
    int* blksum = (int*)alloc(256 * 4);
    int* eslot = (int*)alloc((size_t)E * 4);
    int* ssrc = (int*)alloc((size_t)E * 4);
    float* dinv = (float*)alloc((size_t)N * 4);
    unsigned short* Wp1 = (unsigned short*)alloc(128 * 128 * 2);
    unsigned short* Wp2 = (unsigned short*)alloc(128 * 64 * 2);
    unsigned short* g1 = (unsigned short*)alloc((size_t)N * 128 * 2);  // bf16
    unsigned short* z1 = (unsigned short*)alloc((size_t)N * 128 * 2);  // bf16
    unsigned short* g2 = (unsigned short*)alloc((size_t)N * 64 * 2);   // bf16

    const int nbN = (N + 255) / 256;
    const int nbE = (E + 255) / 256;

    zero_kernel<<<nbN, 256, 0, stream>>>(cnt, N);
    count_kernel<<<nbE, 256, 0, stream>>>(dst, cnt, eslot, E);
    scan1_kernel<<<nbN, 256, 0, stream>>>(cnt, row_ptr, blksum, dinv, N);
    scan2_kernel<<<1, 256, 0, stream>>>(blksum, nbN);
    scan3_kernel<<<nbN, 256, 0, stream>>>(row_ptr, blksum, N, E);
    scatter_kernel<<<nbE, 256, 0, stream>>>(src, dst, row_ptr, eslot, ssrc, E);

    packw_kernel<<<(128 * 128 + 255) / 256, 256, 0, stream>>>(W1, Wp1, 128);
    packw_kernel<<<(128 * 64 + 255) / 256, 256, 0, stream>>>(W2, Wp2, 64);

    const int gb = (N + 63) / 64;
    mfma_gemm_kernel<128, false><<<gb, 256, 0, stream>>>(x, Wp1, dinv, g1, N);
    agg_kernel<128, true, true><<<(N + 3) / 4, 256, 0, stream>>>(g1, row_ptr, ssrc, dinv, b1, z1, N);
    mfma_gemm_kernel<64, true><<<gb, 256, 0, stream>>>(z1, Wp2, dinv, g2, N);
    agg_kernel<64, false, false><<<(N + 3) / 4, 256, 0, stream>>>(g2, row_ptr, ssrc, dinv, b2, out, N);
}